// Round 4
// baseline (458.348 us; speedup 1.0000x reference)
//
#include <hip/hip_runtime.h>
#include <hip/hip_bf16.h>

#define NN 4096
#define DD 256
#define BB 32
#define TT 256
#define EPS 1e-6f
#define DECAY 0.97f
#define LOG2_DECAY -0.043943348f

typedef __hip_bfloat16 bf16;
typedef short short8 __attribute__((ext_vector_type(8)));
typedef float floatx4 __attribute__((ext_vector_type(4)));

__device__ __forceinline__ float bfu2f(short u) {
    return __uint_as_float(((unsigned)(unsigned short)u) << 16);
}

// ---------------- block-wide sum over 256 threads ----------------
__device__ __forceinline__ float blk_sum_256(float v, volatile float* s4) {
#pragma unroll
    for (int o = 32; o > 0; o >>= 1) v += __shfl_down(v, o, 64);
    int lane = threadIdx.x & 63, w = threadIdx.x >> 6;
    __syncthreads();
    if (lane == 0) s4[w] = v;
    __syncthreads();
    return s4[0] + s4[1] + s4[2] + s4[3];
}

// ---------------- dtype detector (bf16-packed vs fp32 inputs) ----------------
__global__ void k_detect(const unsigned short* __restrict__ raw, int* __restrict__ flag) {
    __shared__ int cnt[4];
    int tid = threadIdx.x;
    int bad = 0;
    for (int i = tid; i < 8192; i += 256) {
        unsigned int u = raw[2 * i];
        float v = __uint_as_float(u << 16);
        if (!(fabsf(v) < 1e6f)) bad++;
    }
#pragma unroll
    for (int o = 32; o > 0; o >>= 1) bad += __shfl_down(bad, o, 64);
    int lane = tid & 63, w = tid >> 6;
    if (lane == 0) cnt[w] = bad;
    __syncthreads();
    if (tid == 0) flag[0] = (cnt[0] + cnt[1] + cnt[2] + cnt[3] < 32) ? 1 : 0;
}

// ---------------- convert 3 weight matrices to bf16, 8 elems/thread ----------------
__global__ __launch_bounds__(256) void k_convert3(const void* __restrict__ s0,
                                                  const void* __restrict__ s1,
                                                  const void* __restrict__ s2,
                                                  bf16* __restrict__ d0,
                                                  bf16* __restrict__ d1,
                                                  bf16* __restrict__ d2,
                                                  const int* __restrict__ flag) {
    const int per = NN * DD / 8;
    int i = blockIdx.x * 256 + threadIdx.x;
    int m = i / per, j = i % per;
    const void* s = (m == 0) ? s0 : (m == 1) ? s1 : s2;
    bf16* d = (m == 0) ? d0 : (m == 1) ? d1 : d2;
    if (flag[0]) {
        ((uint4*)d)[j] = ((const uint4*)s)[j];
    } else {
        const float4* f = (const float4*)s;
        float4 a = f[2 * j], b = f[2 * j + 1];
        short8 o;
        float va[8] = {a.x, a.y, a.z, a.w, b.x, b.y, b.z, b.w};
#pragma unroll
        for (int k = 0; k < 8; k++) {
            bf16 t = __float2bfloat16(va[k]);
            o[k] = *reinterpret_cast<short*>(&t);
        }
        ((short8*)d)[j] = o;
    }
}

// ---------------- gather embeddings: Vp (raw) and U=LN(row), both bf16 ----------------
__global__ __launch_bounds__(256) void k_gather_ln(const void* __restrict__ emb,
                                                   const int* __restrict__ idx,
                                                   bf16* __restrict__ Vpb,
                                                   bf16* __restrict__ Ub,
                                                   const int* __restrict__ flag) {
    __shared__ float s4[4];
    int r = blockIdx.x, d = threadIdx.x;
    int tok = idx[r];
    long o = (long)tok * DD + d;
    float e = flag[0] ? __bfloat162float(((const bf16*)emb)[o]) : ((const float*)emb)[o];
    Vpb[(long)r * DD + d] = __float2bfloat16(e);
    float m = blk_sum_256(e, s4) * (1.0f / DD);
    float zc = e - m;
    float var = blk_sum_256(zc * zc, s4) * (1.0f / (DD - 1));
    Ub[(long)r * DD + d] = __float2bfloat16(zc / (sqrtf(fmaxf(var, 0.f)) + EPS));
}

// ---------------- per-batch transpose Ub[b][t][d] -> Ut[b][d][t] ----------------
__global__ __launch_bounds__(256) void k_transpose(const bf16* __restrict__ Ub,
                                                   bf16* __restrict__ Ut) {
    __shared__ bf16 tile[32][33];
    int b = blockIdx.z;
    int t0 = blockIdx.x * 32, d0 = blockIdx.y * 32;
    const bf16* src = Ub + (long)b * TT * DD;
    bf16* dst = Ut + (long)b * DD * TT;
    int rr = threadIdx.x >> 3, c4 = (threadIdx.x & 7) * 4;
#pragma unroll
    for (int i = 0; i < 4; i++) tile[rr][c4 + i] = src[(long)(t0 + rr) * DD + d0 + c4 + i];
    __syncthreads();
#pragma unroll
    for (int i = 0; i < 4; i++) dst[(long)(d0 + rr) * TT + t0 + c4 + i] = tile[c4 + i][rr];
}

// ---------------- MFMA bf16 NT GEMM, DIRECT-GLOBAL fragments (no LDS staging, no
// K-loop barriers). C[m,n] = sum_k A[m,k]*B[n,k]. 128x128 tile, 4 waves of 4x4
// 16x16x32 MFMAs. bf16 epilogues repack via LDS -> coalesced 16B stores.
enum { EPI_RELU_BF16 = 0, EPI_NONE_F32 = 1, EPI_RELU_MULX_BF16 = 2 };

template <int EPI, int KSPLIT, int TRI, int KCHUNK>
__global__ __launch_bounds__(256) void k_mfma_nt(const bf16* __restrict__ A, int lda, long sA,
                                                 const bf16* __restrict__ B, int ldb, long sB,
                                                 void* __restrict__ Cv, int ldc, long sC,
                                                 const bf16* __restrict__ Xaux,
                                                 float* __restrict__ Wsum) {
    int z = blockIdx.z;
    int bz = z / KSPLIT, ks = z % KSPLIT;
    A += (long)bz * sA;
    B += (long)bz * sB;
    int bx = blockIdx.x, by = blockIdx.y;
    if (TRI) {  // 3-tile lower-triangular mapping: 0->(0,0) 1->(1,0) 2->(1,1)
        by = (blockIdx.x >= 1) ? 1 : 0;
        bx = (blockIdx.x == 2) ? 1 : 0;
    }
    int bm = by * 128, bn = bx * 128;
    int tid = threadIdx.x;
    int w = tid >> 6, lane = tid & 63;
    int wm = (w >> 1) * 64, wn = (w & 1) * 64;
    int lm = lane & 15, kh = lane >> 4;

    floatx4 acc[4][4];
#pragma unroll
    for (int i = 0; i < 4; i++)
#pragma unroll
        for (int j = 0; j < 4; j++) acc[i][j] = (floatx4){0.f, 0.f, 0.f, 0.f};

    // lane's base pointers: row picked by lm, 16B k-window picked by kh
    const bf16* pA = A + (long)(bm + wm + lm) * lda + kh * 8 + (long)ks * KCHUNK;
    const bf16* pB = B + (long)(bn + wn + lm) * ldb + kh * 8 + (long)ks * KCHUNK;

#pragma unroll 4
    for (int kk = 0; kk < KCHUNK; kk += 32) {
        short8 af[4], bfr[4];
#pragma unroll
        for (int i = 0; i < 4; i++) af[i] = *(const short8*)(pA + (long)(i * 16) * lda + kk);
#pragma unroll
        for (int j = 0; j < 4; j++) bfr[j] = *(const short8*)(pB + (long)(j * 16) * ldb + kk);
#pragma unroll
        for (int i = 0; i < 4; i++)
#pragma unroll
            for (int j = 0; j < 4; j++)
                acc[i][j] = __builtin_amdgcn_mfma_f32_16x16x32_bf16(af[i], bfr[j], acc[i][j], 0, 0, 0);
    }

    if (EPI == EPI_NONE_F32) {
        long cbase = (long)z * sC;
#pragma unroll
        for (int i = 0; i < 4; i++)
#pragma unroll
            for (int j = 0; j < 4; j++)
#pragma unroll
                for (int r = 0; r < 4; r++) {
                    int gm = bm + wm + i * 16 + kh * 4 + r;
                    int gn = bn + wn + j * 16 + lm;
                    ((float*)Cv)[cbase + (long)gm * ldc + gn] = acc[i][j][r];
                }
        return;
    }

    // ---- LDS-repack epilogue: two 64-row passes, coalesced 16B stores ----
    __shared__ __align__(16) bf16 R[64 * 136];
#pragma unroll
    for (int p = 0; p < 2; p++) {
        __syncthreads();
        if ((w >> 1) == p) {
#pragma unroll
            for (int i = 0; i < 4; i++)
#pragma unroll
                for (int j = 0; j < 4; j++)
#pragma unroll
                    for (int r = 0; r < 4; r++) {
                        int rr = i * 16 + kh * 4 + r;
                        int cc = wn + j * 16 + lm;
                        R[rr * 136 + cc] = __float2bfloat16(fmaxf(acc[i][j][r], 0.f));
                    }
        }
        __syncthreads();
#pragma unroll
        for (int it = 0; it < 4; it++) {
            int row_l = it * 16 + (tid >> 4);
            int c8 = (tid & 15) * 8;
            short8 vv = *(const short8*)(R + row_l * 136 + c8);
            int gm = bm + p * 64 + row_l;
            long off = (long)gm * ldc + bn + c8;
            if (EPI == EPI_RELU_BF16) {
                *(short8*)((bf16*)Cv + off) = vv;
                float s = 0.f;
#pragma unroll
                for (int k = 0; k < 8; k++) s += bfu2f(vv[k]);
#pragma unroll
                for (int o = 8; o > 0; o >>= 1) s += __shfl_down(s, o, 16);
                if ((tid & 15) == 0) atomicAdd(&Wsum[gm], s);
            } else {  // EPI_RELU_MULX_BF16
                short8 xx = *(const short8*)(Xaux + off);
                short8 oo;
#pragma unroll
                for (int k = 0; k < 8; k++) {
                    float prod = bfu2f(vv[k]) * fmaxf(bfu2f(xx[k]), 0.f);
                    bf16 t = __float2bfloat16(prod);
                    oo[k] = *reinterpret_cast<short*>(&t);
                }
                *(short8*)((bf16*)Cv + off) = oo;
            }
        }
    }
}

// ---------------- scalar normalizer recurrence ----------------
__global__ __launch_bounds__(256) void k_scalar_scan(const float* __restrict__ Wsum,
                                                     float* __restrict__ invS) {
    __shared__ float sw[BB * TT];
    for (int i = threadIdx.x; i < BB * TT; i += 256) sw[i] = Wsum[i];
    __syncthreads();
    int b = threadIdx.x;
    if (b < BB) {
        float sig = 0.f;
        for (int t = 0; t < TT; t++) {
            float S = DECAY * sig + sw[b * TT + t];
            float inv = 1.f / (S + EPS);
            invS[b * TT + t] = inv;
            sig = S * inv;
        }
    }
}

// ---------------- barrier-free column scan: x = (0.97 x + w) * invS[t] ----------------
__global__ __launch_bounds__(256) void k_colscan(bf16* __restrict__ W,
                                                 const float* __restrict__ invS) {
    __shared__ float sv[TT];
    int b = blockIdx.y;
    sv[threadIdx.x] = invS[b * TT + threadIdx.x];
    __syncthreads();
    int n = blockIdx.x * 256 + threadIdx.x;
    bf16* p = W + (long)b * TT * NN + n;
    float x = 0.f;
    for (int t = 0; t < TT; t++) {
        float w = __bfloat162float(p[(long)t * NN]);
        x = (DECAY * x + w) * sv[t];
        p[(long)t * NN] = __float2bfloat16(x);
    }
}

// ---------------- reduce 4 split-K score partials + causal decay mask -> G bf16 ----------------
__global__ __launch_bounds__(256) void k_reduce_mask(const float* __restrict__ Gp,
                                                     bf16* __restrict__ G) {
    int r = blockIdx.x;
    int b = r >> 8, t = r & 255;
    int s = threadIdx.x;
    long base = ((long)b * 4) * 65536 + (long)t * 256 + s;
    float v = Gp[base] + Gp[base + 65536] + Gp[base + 2 * 65536] + Gp[base + 3 * 65536];
    float o = (s < t) ? v * exp2f((float)(t - s) * LOG2_DECAY) : 0.f;
    G[(long)r * 256 + s] = __float2bfloat16(o);
}

// ---------------- sum 2 attn split-K partials + row layernorm -> ALN bf16 ----------------
__global__ __launch_bounds__(256) void k_ln_rows(const float* __restrict__ Zp,
                                                 bf16* __restrict__ O) {
    __shared__ float s4[4];
    long r = blockIdx.x;
    int d = threadIdx.x;
    long b = r >> 8, t = r & 255;
    long base = (b * 2) * 65536 + t * 256 + d;
    float z = Zp[base] + Zp[base + 65536];
    float m = blk_sum_256(z, s4) * (1.0f / DD);
    float zc = z - m;
    float var = blk_sum_256(zc * zc, s4) * (1.0f / (DD - 1));
    O[r * DD + d] = __float2bfloat16(zc / (sqrtf(fmaxf(var, 0.f)) + EPS));
}

// ---------------- sum 4 split-K Z partials + layernorm -> output ----------------
__global__ __launch_bounds__(256) void k_final_ln(const float* __restrict__ Zp,
                                                  void* __restrict__ out,
                                                  const int* __restrict__ flag) {
    __shared__ float s4[4];
    long r = blockIdx.x;
    int d = threadIdx.x;
    const long SL = (long)8192 * 256;
    long o = r * DD + d;
    float z = Zp[o] + Zp[o + SL] + Zp[o + 2 * SL] + Zp[o + 3 * SL];
    float m = blk_sum_256(z, s4) * (1.0f / DD);
    float zc = z - m;
    float var = blk_sum_256(zc * zc, s4) * (1.0f / (DD - 1));
    float v = zc / (sqrtf(fmaxf(var, 0.f)) + EPS);
    if (flag[0]) ((bf16*)out)[o] = __float2bfloat16(v);
    else ((float*)out)[o] = v;
}

extern "C" void kernel_launch(void* const* d_in, const int* in_sizes, int n_in,
                              void* d_out, int out_size, void* d_ws, size_t ws_size,
                              hipStream_t stream) {
    const int* idx = (const int*)d_in[0];
    const void* emb = d_in[1];
    const void* E = d_in[2];
    const void* Dx = d_in[3];
    const void* Dy = d_in[4];

    // ---- workspace carve (bytes) ----
    char* base = (char*)d_ws;
    size_t off = 0;
    int* flag = (int*)base; off += 1024;
    bf16* Dxb = (bf16*)(base + off); off += (size_t)NN * DD * 2;
    bf16* Dyb = (bf16*)(base + off); off += (size_t)NN * DD * 2;
    bf16* Eb  = (bf16*)(base + off); off += (size_t)DD * NN * 2;
    bf16* Vpb = (bf16*)(base + off); off += (size_t)BB * TT * DD * 2;
    bf16* Ub  = (bf16*)(base + off); off += (size_t)BB * TT * DD * 2;
    bf16* Ut  = (bf16*)(base + off); off += (size_t)BB * TT * DD * 2;
    float* Wsum = (float*)(base + off); off += (size_t)BB * TT * 4;
    float* invS = (float*)(base + off); off += (size_t)BB * TT * 4;
    bf16* ALNb = (bf16*)(base + off); off += (size_t)BB * TT * DD * 2;
    bf16* G = (bf16*)(base + off); off += (size_t)BB * TT * TT * 2;
    float* Gp = (float*)(base + off); off += (size_t)4 * BB * TT * TT * 4;  // 33.5MB
    float* Astar = Gp;  // attn partials alias Gp
    float* Zp = Gp;     // Z partials alias Gp
    bf16* Xb = (bf16*)(base + off); off += (size_t)BB * TT * NN * 2;        // 67MB

    const int M = BB * TT;  // 8192

    k_detect<<<1, 256, 0, stream>>>((const unsigned short*)emb, flag);
    k_convert3<<<3 * NN * DD / 8 / 256, 256, 0, stream>>>(Dx, Dy, E, Dxb, Dyb, Eb, flag);
    k_gather_ln<<<M, 256, 0, stream>>>(emb, idx, Vpb, Ub, flag);
    k_transpose<<<dim3(8, 8, BB), 256, 0, stream>>>(Ub, Ut);

    hipMemsetAsync(Wsum, 0, (size_t)M * 4, stream);

    // W = relu(Vp @ Dx^T) -> Xb (bf16), rowsums fused via atomics
    k_mfma_nt<EPI_RELU_BF16, 1, 0, 256><<<dim3(32, 64, 1), 256, 0, stream>>>(
        Vpb, DD, 0, Dxb, DD, 0, Xb, NN, 0, nullptr, Wsum);

    k_scalar_scan<<<1, 256, 0, stream>>>(Wsum, invS);
    k_colscan<<<dim3(16, BB, 1), 256, 0, stream>>>(Xb, invS);

    // scores partials: 3 lower-triangular tiles, batched b, split-K 4 (kchunk 1024)
    k_mfma_nt<EPI_NONE_F32, 4, 1, 1024><<<dim3(3, 1, BB * 4), 256, 0, stream>>>(
        Xb, NN, (long)TT * NN, Xb, NN, (long)TT * NN, Gp, TT, (long)TT * TT, nullptr, nullptr);
    k_reduce_mask<<<M, 256, 0, stream>>>(Gp, G);

    // a* partials = Gm @ U (NT with Ut), batched, split-K 2 (kchunk 128)
    k_mfma_nt<EPI_NONE_F32, 2, 0, 128><<<dim3(2, 2, BB * 2), 256, 0, stream>>>(
        G, TT, (long)TT * TT, Ut, TT, (long)DD * TT, Astar, DD, (long)TT * DD, nullptr, nullptr);
    k_ln_rows<<<M, 256, 0, stream>>>(Astar, ALNb);

    // Y = relu(ALN @ Dy^T) * relu(X), in place over Xb
    k_mfma_nt<EPI_RELU_MULX_BF16, 1, 0, 256><<<dim3(32, 64, 1), 256, 0, stream>>>(
        ALNb, DD, 0, Dyb, DD, 0, Xb, NN, 0, Xb, nullptr);

    // Z partials = Y @ E^T (split-K 4, kchunk 1024)
    k_mfma_nt<EPI_NONE_F32, 4, 0, 1024><<<dim3(2, 64, 4), 256, 0, stream>>>(
        Xb, NN, 0, Eb, NN, 0, Zp, DD, (long)M * DD, nullptr, nullptr);

    k_final_ln<<<M, 256, 0, stream>>>(Zp, d_out, flag);
}

// Round 5
// 363.006 us; speedup vs baseline: 1.2626x; 1.2626x over previous
//
#include <hip/hip_runtime.h>
#include <hip/hip_bf16.h>

#define NN 4096
#define DD 256
#define BB 32
#define TT 256
#define EPS 1e-6f
#define DECAY 0.97f
#define LOG2_DECAY -0.043943348f

typedef __hip_bfloat16 bf16;
typedef short short8 __attribute__((ext_vector_type(8)));
typedef float floatx4 __attribute__((ext_vector_type(4)));

__device__ __forceinline__ float bfu2f(short u) {
    return __uint_as_float(((unsigned)(unsigned short)u) << 16);
}

// ---------------- block-wide sum over 256 threads ----------------
__device__ __forceinline__ float blk_sum_256(float v, volatile float* s4) {
#pragma unroll
    for (int o = 32; o > 0; o >>= 1) v += __shfl_down(v, o, 64);
    int lane = threadIdx.x & 63, w = threadIdx.x >> 6;
    __syncthreads();
    if (lane == 0) s4[w] = v;
    __syncthreads();
    return s4[0] + s4[1] + s4[2] + s4[3];
}

// async global->LDS, 16B per lane; LDS dest is wave-uniform base + lane*16
__device__ __forceinline__ void gl16(const bf16* g, bf16* l) {
    __builtin_amdgcn_global_load_lds((const __attribute__((address_space(1))) void*)g,
                                     (__attribute__((address_space(3))) void*)l, 16, 0, 0);
}

// ---------------- dtype detector (bf16-packed vs fp32 inputs) ----------------
__global__ void k_detect(const unsigned short* __restrict__ raw, int* __restrict__ flag) {
    __shared__ int cnt[4];
    int tid = threadIdx.x;
    int bad = 0;
    for (int i = tid; i < 8192; i += 256) {
        unsigned int u = raw[2 * i];
        float v = __uint_as_float(u << 16);
        if (!(fabsf(v) < 1e6f)) bad++;
    }
#pragma unroll
    for (int o = 32; o > 0; o >>= 1) bad += __shfl_down(bad, o, 64);
    int lane = tid & 63, w = tid >> 6;
    if (lane == 0) cnt[w] = bad;
    __syncthreads();
    if (tid == 0) flag[0] = (cnt[0] + cnt[1] + cnt[2] + cnt[3] < 32) ? 1 : 0;
}

// ---------------- convert 3 weight matrices to bf16, 8 elems/thread ----------------
__global__ __launch_bounds__(256) void k_convert3(const void* __restrict__ s0,
                                                  const void* __restrict__ s1,
                                                  const void* __restrict__ s2,
                                                  bf16* __restrict__ d0,
                                                  bf16* __restrict__ d1,
                                                  bf16* __restrict__ d2,
                                                  const int* __restrict__ flag) {
    const int per = NN * DD / 8;
    int i = blockIdx.x * 256 + threadIdx.x;
    int m = i / per, j = i % per;
    const void* s = (m == 0) ? s0 : (m == 1) ? s1 : s2;
    bf16* d = (m == 0) ? d0 : (m == 1) ? d1 : d2;
    if (flag[0]) {
        ((uint4*)d)[j] = ((const uint4*)s)[j];
    } else {
        const float4* f = (const float4*)s;
        float4 a = f[2 * j], b = f[2 * j + 1];
        short8 o;
        float va[8] = {a.x, a.y, a.z, a.w, b.x, b.y, b.z, b.w};
#pragma unroll
        for (int k = 0; k < 8; k++) {
            bf16 t = __float2bfloat16(va[k]);
            o[k] = *reinterpret_cast<short*>(&t);
        }
        ((short8*)d)[j] = o;
    }
}

// ---------------- gather embeddings: Vp (raw) and U=LN(row), both bf16 ----------------
__global__ __launch_bounds__(256) void k_gather_ln(const void* __restrict__ emb,
                                                   const int* __restrict__ idx,
                                                   bf16* __restrict__ Vpb,
                                                   bf16* __restrict__ Ub,
                                                   const int* __restrict__ flag) {
    __shared__ float s4[4];
    int r = blockIdx.x, d = threadIdx.x;
    int tok = idx[r];
    long o = (long)tok * DD + d;
    float e = flag[0] ? __bfloat162float(((const bf16*)emb)[o]) : ((const float*)emb)[o];
    Vpb[(long)r * DD + d] = __float2bfloat16(e);
    float m = blk_sum_256(e, s4) * (1.0f / DD);
    float zc = e - m;
    float var = blk_sum_256(zc * zc, s4) * (1.0f / (DD - 1));
    Ub[(long)r * DD + d] = __float2bfloat16(zc / (sqrtf(fmaxf(var, 0.f)) + EPS));
}

// ---------------- per-batch transpose Ub[b][t][d] -> Ut[b][d][t] ----------------
__global__ __launch_bounds__(256) void k_transpose(const bf16* __restrict__ Ub,
                                                   bf16* __restrict__ Ut) {
    __shared__ bf16 tile[32][33];
    int b = blockIdx.z;
    int t0 = blockIdx.x * 32, d0 = blockIdx.y * 32;
    const bf16* src = Ub + (long)b * TT * DD;
    bf16* dst = Ut + (long)b * DD * TT;
    int rr = threadIdx.x >> 3, c4 = (threadIdx.x & 7) * 4;
#pragma unroll
    for (int i = 0; i < 4; i++) tile[rr][c4 + i] = src[(long)(t0 + rr) * DD + d0 + c4 + i];
    __syncthreads();
#pragma unroll
    for (int i = 0; i < 4; i++) dst[(long)(d0 + rr) * TT + t0 + c4 + i] = tile[c4 + i][rr];
}

// =====================================================================
// Whole-K (K=256) MFMA NT GEMM, 64x64 tile. Entire A/B K-extent staged in
// LDS once (XOR-swizzled 16B chunks -> conflict-free ds_read_b128), single
// barrier, then 8 barrier-free k-steps. 64KB LDS -> 2 blocks/CU.
// =====================================================================
enum { EPI_RELU_BF16 = 0, EPI_NONE_F32 = 1, EPI_RELU_MULX_BF16 = 2 };

template <int EPI>
__global__ __launch_bounds__(256) void k_wk64(const bf16* __restrict__ A, int lda, long sA,
                                              const bf16* __restrict__ B, int ldb, long sB,
                                              void* __restrict__ Cv, int ldc, long sC,
                                              const bf16* __restrict__ Xaux,
                                              float* __restrict__ Wsum) {
    __shared__ __align__(16) bf16 As[16384];  // 64 rows x 256 k, chunk-swizzled
    __shared__ __align__(16) bf16 Bs[16384];
    int z = blockIdx.z;
    A += (long)z * sA;
    B += (long)z * sB;
    long cbase = (long)z * sC;
    int bm = blockIdx.y * 64, bn = blockIdx.x * 64;
    int tid = threadIdx.x, w = tid >> 6, lane = tid & 63;
    int half = lane >> 5, c32 = lane & 31;

    // ---- stage whole tiles: per wave 8 row-pairs of A and B (16 gl16) ----
    // phys chunk slot (lane&31) holds logical chunk (lane&31)^(row&31).
#pragma unroll
    for (int jj = 0; jj < 8; jj++) {
        int j = w * 8 + jj;  // row-pair 0..31
        int r = 2 * j + half;
        int cs = c32 ^ (r & 31);
        gl16(A + (long)(bm + r) * lda + cs * 8, As + j * 512);
        gl16(B + (long)(bn + r) * ldb + cs * 8, Bs + j * 512);
    }
    __syncthreads();  // single drain for the whole K-loop

    int wm = (w >> 1) * 32, wn = (w & 1) * 32;
    int lm = lane & 15, kh = lane >> 4;
    floatx4 acc[2][2];
#pragma unroll
    for (int i = 0; i < 2; i++)
#pragma unroll
        for (int j = 0; j < 2; j++) acc[i][j] = (floatx4){0.f, 0.f, 0.f, 0.f};

#pragma unroll
    for (int ks = 0; ks < 8; ks++) {
        int C = ks * 4 + kh;
        short8 af[2], bfr[2];
#pragma unroll
        for (int i = 0; i < 2; i++) {
            int ra = wm + i * 16 + lm;
            af[i] = *(const short8*)(As + ra * 256 + ((C ^ (ra & 31)) << 3));
            int rb = wn + i * 16 + lm;
            bfr[i] = *(const short8*)(Bs + rb * 256 + ((C ^ (rb & 31)) << 3));
        }
#pragma unroll
        for (int i = 0; i < 2; i++)
#pragma unroll
            for (int j = 0; j < 2; j++)
                acc[i][j] = __builtin_amdgcn_mfma_f32_16x16x32_bf16(af[i], bfr[j], acc[i][j], 0, 0, 0);
    }

    if (EPI == EPI_NONE_F32) {
#pragma unroll
        for (int i = 0; i < 2; i++)
#pragma unroll
            for (int j = 0; j < 2; j++)
#pragma unroll
                for (int r = 0; r < 4; r++) {
                    int gm = bm + wm + i * 16 + kh * 4 + r;
                    int gn = bn + wn + j * 16 + lm;
                    ((float*)Cv)[cbase + (long)gm * ldc + gn] = acc[i][j][r];
                }
        return;
    }

    // ---- LDS repack (reuse As) -> coalesced 16B bf16 stores ----
    __syncthreads();
    bf16* R = As;  // [64][72]
#pragma unroll
    for (int i = 0; i < 2; i++)
#pragma unroll
        for (int j = 0; j < 2; j++)
#pragma unroll
            for (int r = 0; r < 4; r++) {
                int rr = wm + i * 16 + kh * 4 + r;
                int cc = wn + j * 16 + lm;
                R[rr * 72 + cc] = __float2bfloat16(fmaxf(acc[i][j][r], 0.f));
            }
    __syncthreads();
#pragma unroll
    for (int it = 0; it < 2; it++) {
        int slot = it * 256 + tid;
        int row = slot >> 3, c8 = (slot & 7) * 8;
        short8 vv = *(const short8*)(R + row * 72 + c8);
        int gm = bm + row;
        long off = cbase + (long)gm * ldc + bn + c8;
        if (EPI == EPI_RELU_BF16) {
            *(short8*)((bf16*)Cv + off) = vv;
            float s = 0.f;
#pragma unroll
            for (int k = 0; k < 8; k++) s += bfu2f(vv[k]);
            s += __shfl_down(s, 4, 8);
            s += __shfl_down(s, 2, 8);
            s += __shfl_down(s, 1, 8);
            if ((tid & 7) == 0) atomicAdd(&Wsum[gm], s);
        } else {  // EPI_RELU_MULX_BF16
            short8 xx = *(const short8*)(Xaux + off);
            short8 oo;
#pragma unroll
            for (int k = 0; k < 8; k++) {
                float prod = bfu2f(vv[k]) * fmaxf(bfu2f(xx[k]), 0.f);
                bf16 t = __float2bfloat16(prod);
                oo[k] = *reinterpret_cast<short*>(&t);
            }
            *(short8*)((bf16*)Cv + off) = oo;
        }
    }
}

// =====================================================================
// Pipelined MFMA NT GEMM for large K (scores, Z): 128x128 tile, BK=32,
// global_load_lds staging (R3-proven), f32 output only.
// =====================================================================
template <int KSPLIT, int TRI>
__global__ __launch_bounds__(256) void k_pipe(int K,
                                              const bf16* __restrict__ A, int lda, long sA,
                                              const bf16* __restrict__ B, int ldb, long sB,
                                              float* __restrict__ Cv, int ldc, long sC) {
    __shared__ __align__(16) bf16 As[128 * 32];
    __shared__ __align__(16) bf16 Bs[128 * 32];
    int z = blockIdx.z;
    int bz = z / KSPLIT, ks = z % KSPLIT;
    A += (long)bz * sA;
    B += (long)bz * sB;
    int bx = blockIdx.x, by = blockIdx.y;
    if (TRI) {  // 3-tile lower-triangular mapping
        by = (blockIdx.x >= 1) ? 1 : 0;
        bx = (blockIdx.x == 2) ? 1 : 0;
    }
    int bm = by * 128, bn = bx * 128;
    int tid = threadIdx.x;
    int srow = tid >> 2, scol = (tid & 3) << 3;
    int w = tid >> 6, lane = tid & 63;
    int wm = (w >> 1) * 64, wn = (w & 1) * 64;
    int lm = lane & 15, kh = lane >> 4;

    floatx4 acc[4][4];
#pragma unroll
    for (int i = 0; i < 4; i++)
#pragma unroll
        for (int j = 0; j < 4; j++) acc[i][j] = (floatx4){0.f, 0.f, 0.f, 0.f};

    int kchunk = K / KSPLIT;
    int kbeg = ks * kchunk, kend = kbeg + kchunk;
    const bf16* gA0 = A + (long)(bm + srow) * lda + scol;
    const bf16* gA1 = gA0 + (long)64 * lda;
    const bf16* gB0 = B + (long)(bn + srow) * ldb + scol;
    const bf16* gB1 = gB0 + (long)64 * ldb;
    bf16* lA0 = As + srow * 32 + scol;
    bf16* lA1 = As + (srow + 64) * 32 + scol;
    bf16* lB0 = Bs + srow * 32 + scol;
    bf16* lB1 = Bs + (srow + 64) * 32 + scol;

    for (int k0 = kbeg; k0 < kend; k0 += 32) {
        __syncthreads();
        gl16(gA0 + k0, lA0);
        gl16(gA1 + k0, lA1);
        gl16(gB0 + k0, lB0);
        gl16(gB1 + k0, lB1);
        __syncthreads();
        short8 af[4], bfr[4];
#pragma unroll
        for (int i = 0; i < 4; i++) af[i] = *(const short8*)(As + (wm + i * 16 + lm) * 32 + kh * 8);
#pragma unroll
        for (int j = 0; j < 4; j++) bfr[j] = *(const short8*)(Bs + (wn + j * 16 + lm) * 32 + kh * 8);
#pragma unroll
        for (int i = 0; i < 4; i++)
#pragma unroll
            for (int j = 0; j < 4; j++)
                acc[i][j] = __builtin_amdgcn_mfma_f32_16x16x32_bf16(af[i], bfr[j], acc[i][j], 0, 0, 0);
    }

    long cbase = (long)z * sC;
#pragma unroll
    for (int i = 0; i < 4; i++)
#pragma unroll
        for (int j = 0; j < 4; j++)
#pragma unroll
            for (int r = 0; r < 4; r++) {
                int gm = bm + wm + i * 16 + kh * 4 + r;
                int gn = bn + wn + j * 16 + lm;
                Cv[cbase + (long)gm * ldc + gn] = acc[i][j][r];
            }
}

// ---------------- scalar normalizer recurrence ----------------
__global__ __launch_bounds__(256) void k_scalar_scan(const float* __restrict__ Wsum,
                                                     float* __restrict__ invS) {
    __shared__ float sw[BB * TT];
    for (int i = threadIdx.x; i < BB * TT; i += 256) sw[i] = Wsum[i];
    __syncthreads();
    int b = threadIdx.x;
    if (b < BB) {
        float sig = 0.f;
        for (int t = 0; t < TT; t++) {
            float S = DECAY * sig + sw[b * TT + t];
            float inv = 1.f / (S + EPS);
            invS[b * TT + t] = inv;
            sig = S * inv;
        }
    }
}

// ---------------- column scan, 4 independent chains per thread ----------------
__global__ __launch_bounds__(256) void k_colscan(bf16* __restrict__ W,
                                                 const float* __restrict__ invS) {
    __shared__ float sv[TT];
    int b = blockIdx.y;
    sv[threadIdx.x] = invS[b * TT + threadIdx.x];
    __syncthreads();
    int n0 = blockIdx.x * 1024 + threadIdx.x * 4;
    bf16* p = W + (long)b * TT * NN + n0;
    float x0 = 0.f, x1 = 0.f, x2 = 0.f, x3 = 0.f;
    for (int t = 0; t < TT; t++) {
        short4 wv = *(const short4*)(p + (long)t * NN);
        float iv = sv[t];
        x0 = (DECAY * x0 + bfu2f(wv.x)) * iv;
        x1 = (DECAY * x1 + bfu2f(wv.y)) * iv;
        x2 = (DECAY * x2 + bfu2f(wv.z)) * iv;
        x3 = (DECAY * x3 + bfu2f(wv.w)) * iv;
        short4 ov;
        bf16 t0 = __float2bfloat16(x0), t1 = __float2bfloat16(x1);
        bf16 t2 = __float2bfloat16(x2), t3 = __float2bfloat16(x3);
        ov.x = *reinterpret_cast<short*>(&t0);
        ov.y = *reinterpret_cast<short*>(&t1);
        ov.z = *reinterpret_cast<short*>(&t2);
        ov.w = *reinterpret_cast<short*>(&t3);
        *(short4*)(p + (long)t * NN) = ov;
    }
}

// ---------------- reduce 4 split-K score partials + causal decay mask -> G bf16 ----------------
__global__ __launch_bounds__(256) void k_reduce_mask(const float* __restrict__ Gp,
                                                     bf16* __restrict__ G) {
    int r = blockIdx.x;
    int b = r >> 8, t = r & 255;
    int s = threadIdx.x;
    float o = 0.f;
    if (s < t) {
        long base = ((long)b * 4) * 65536 + (long)t * 256 + s;
        float v = Gp[base] + Gp[base + 65536] + Gp[base + 2 * 65536] + Gp[base + 3 * 65536];
        o = v * exp2f((float)(t - s) * LOG2_DECAY);
    }
    G[(long)r * 256 + s] = __float2bfloat16(o);
}

// ---------------- row layernorm Astar (fp32) -> ALN bf16 ----------------
__global__ __launch_bounds__(256) void k_ln_rows(const float* __restrict__ Z,
                                                 bf16* __restrict__ O) {
    __shared__ float s4[4];
    long r = blockIdx.x;
    int d = threadIdx.x;
    float z = Z[r * DD + d];
    float m = blk_sum_256(z, s4) * (1.0f / DD);
    float zc = z - m;
    float var = blk_sum_256(zc * zc, s4) * (1.0f / (DD - 1));
    O[r * DD + d] = __float2bfloat16(zc / (sqrtf(fmaxf(var, 0.f)) + EPS));
}

// ---------------- sum 4 split-K Z partials + layernorm -> output ----------------
__global__ __launch_bounds__(256) void k_final_ln(const float* __restrict__ Zp,
                                                  void* __restrict__ out,
                                                  const int* __restrict__ flag) {
    __shared__ float s4[4];
    long r = blockIdx.x;
    int d = threadIdx.x;
    const long SL = (long)8192 * 256;
    long o = r * DD + d;
    float z = Zp[o] + Zp[o + SL] + Zp[o + 2 * SL] + Zp[o + 3 * SL];
    float m = blk_sum_256(z, s4) * (1.0f / DD);
    float zc = z - m;
    float var = blk_sum_256(zc * zc, s4) * (1.0f / (DD - 1));
    float v = zc / (sqrtf(fmaxf(var, 0.f)) + EPS);
    if (flag[0]) ((bf16*)out)[o] = __float2bfloat16(v);
    else ((float*)out)[o] = v;
}

extern "C" void kernel_launch(void* const* d_in, const int* in_sizes, int n_in,
                              void* d_out, int out_size, void* d_ws, size_t ws_size,
                              hipStream_t stream) {
    const int* idx = (const int*)d_in[0];
    const void* emb = d_in[1];
    const void* E = d_in[2];
    const void* Dx = d_in[3];
    const void* Dy = d_in[4];

    // ---- workspace carve (bytes) ----
    char* base = (char*)d_ws;
    size_t off = 0;
    int* flag = (int*)base; off += 1024;
    bf16* Dxb = (bf16*)(base + off); off += (size_t)NN * DD * 2;
    bf16* Dyb = (bf16*)(base + off); off += (size_t)NN * DD * 2;
    bf16* Eb  = (bf16*)(base + off); off += (size_t)DD * NN * 2;
    bf16* Vpb = (bf16*)(base + off); off += (size_t)BB * TT * DD * 2;
    bf16* Ub  = (bf16*)(base + off); off += (size_t)BB * TT * DD * 2;
    bf16* Ut  = (bf16*)(base + off); off += (size_t)BB * TT * DD * 2;
    float* Wsum = (float*)(base + off); off += (size_t)BB * TT * 4;
    float* invS = (float*)(base + off); off += (size_t)BB * TT * 4;
    bf16* ALNb = (bf16*)(base + off); off += (size_t)BB * TT * DD * 2;
    bf16* G = (bf16*)(base + off); off += (size_t)BB * TT * TT * 2;
    float* Gp = (float*)(base + off); off += (size_t)4 * BB * TT * TT * 4;  // 33.5MB
    float* Astar = Gp;  // full (non-split) a* aliases Gp after reduce_mask
    float* Zp = Gp;     // Z partials alias Gp after ln_rows
    bf16* Xb = (bf16*)(base + off); off += (size_t)BB * TT * NN * 2;        // 67MB

    const int M = BB * TT;  // 8192

    k_detect<<<1, 256, 0, stream>>>((const unsigned short*)emb, flag);
    k_convert3<<<3 * NN * DD / 8 / 256, 256, 0, stream>>>(Dx, Dy, E, Dxb, Dyb, Eb, flag);
    k_gather_ln<<<M, 256, 0, stream>>>(emb, idx, Vpb, Ub, flag);
    k_transpose<<<dim3(8, 8, BB), 256, 0, stream>>>(Ub, Ut);

    hipMemsetAsync(Wsum, 0, (size_t)M * 4, stream);

    // W = relu(Vp @ Dx^T) -> Xb (bf16), rowsums fused via atomics (whole-K)
    k_wk64<EPI_RELU_BF16><<<dim3(NN / 64, M / 64, 1), 256, 0, stream>>>(
        Vpb, DD, 0, Dxb, DD, 0, Xb, NN, 0, nullptr, Wsum);

    k_scalar_scan<<<1, 256, 0, stream>>>(Wsum, invS);
    k_colscan<<<dim3(4, BB, 1), 256, 0, stream>>>(Xb, invS);

    // scores partials: 3 lower-triangular tiles, batched, split-K 4 (pipelined)
    k_pipe<4, 1><<<dim3(3, 1, BB * 4), 256, 0, stream>>>(
        NN, Xb, NN, (long)TT * NN, Xb, NN, (long)TT * NN, Gp, TT, (long)TT * TT);
    k_reduce_mask<<<M, 256, 0, stream>>>(Gp, G);

    // a* = Gm @ U (NT with Ut), batched, whole-K, no split
    k_wk64<EPI_NONE_F32><<<dim3(TT / 64, TT / 64, BB), 256, 0, stream>>>(
        G, TT, (long)TT * TT, Ut, TT, (long)DD * TT, Astar, DD, (long)TT * DD, nullptr, nullptr);
    k_ln_rows<<<M, 256, 0, stream>>>(Astar, ALNb);

    // Y = relu(ALN @ Dy^T) * relu(X), in place over Xb (whole-K)
    k_wk64<EPI_RELU_MULX_BF16><<<dim3(NN / 64, M / 64, 1), 256, 0, stream>>>(
        ALNb, DD, 0, Dyb, DD, 0, Xb, NN, 0, Xb, nullptr);

    // Z partials = Y @ E^T (split-K 4, pipelined)
    k_pipe<4, 0><<<dim3(2, 64, 4), 256, 0, stream>>>(
        NN, Xb, NN, 0, Eb, NN, 0, Zp, DD, (long)M * DD);

    k_final_ln<<<M, 256, 0, stream>>>(Zp, d_out, flag);
}

// Round 6
// 341.963 us; speedup vs baseline: 1.3403x; 1.0615x over previous
//
#include <hip/hip_runtime.h>
#include <hip/hip_bf16.h>

#define NN 4096
#define DD 256
#define BB 32
#define TT 256
#define EPS 1e-6f
#define DECAY 0.97f
#define LOG2_DECAY -0.043943348f

typedef __hip_bfloat16 bf16;
typedef short short8 __attribute__((ext_vector_type(8)));
typedef float floatx4 __attribute__((ext_vector_type(4)));

__device__ __forceinline__ float bfu2f(short u) {
    return __uint_as_float(((unsigned)(unsigned short)u) << 16);
}
__device__ __forceinline__ short f2bfu(float v) {
    bf16 t = __float2bfloat16(v);
    return *reinterpret_cast<short*>(&t);
}

// ---------------- block-wide sum over 256 threads ----------------
__device__ __forceinline__ float blk_sum_256(float v, volatile float* s4) {
#pragma unroll
    for (int o = 32; o > 0; o >>= 1) v += __shfl_down(v, o, 64);
    int lane = threadIdx.x & 63, w = threadIdx.x >> 6;
    __syncthreads();
    if (lane == 0) s4[w] = v;
    __syncthreads();
    return s4[0] + s4[1] + s4[2] + s4[3];
}

// async global->LDS, 16B per lane; dest must be wave-uniform base + lane*16
__device__ __forceinline__ void gl16(const bf16* g, void* l) {
    __builtin_amdgcn_global_load_lds((const __attribute__((address_space(1))) void*)g,
                                     (__attribute__((address_space(3))) void*)l, 16, 0, 0);
}

// XOR-swizzled fragment read: 16B at (row, k-chunk c) with BK=64 rows (128B/row).
// bank-quad = c ^ (row&7) -> conflict-free for MFMA frag pattern.
__device__ __forceinline__ short8 frag(const char* matbase, int row, int c) {
    return *(const short8*)(matbase + row * 128 + (((c) ^ (row & 7)) << 4));
}

// ---------------- dtype detector (bf16-packed vs fp32 inputs) ----------------
__global__ void k_detect(const unsigned short* __restrict__ raw, int* __restrict__ flag) {
    __shared__ int cnt[4];
    int tid = threadIdx.x;
    int bad = 0;
    for (int i = tid; i < 8192; i += 256) {
        unsigned int u = raw[2 * i];
        float v = __uint_as_float(u << 16);
        if (!(fabsf(v) < 1e6f)) bad++;
    }
#pragma unroll
    for (int o = 32; o > 0; o >>= 1) bad += __shfl_down(bad, o, 64);
    int lane = tid & 63, w = tid >> 6;
    if (lane == 0) cnt[w] = bad;
    __syncthreads();
    if (tid == 0) flag[0] = (cnt[0] + cnt[1] + cnt[2] + cnt[3] < 32) ? 1 : 0;
}

// ---------------- convert 3 weight matrices to bf16 ----------------
__global__ __launch_bounds__(256) void k_convert3(const void* __restrict__ s0,
                                                  const void* __restrict__ s1,
                                                  const void* __restrict__ s2,
                                                  bf16* __restrict__ d0,
                                                  bf16* __restrict__ d1,
                                                  bf16* __restrict__ d2,
                                                  const int* __restrict__ flag) {
    const int per = NN * DD / 8;
    int i = blockIdx.x * 256 + threadIdx.x;
    int m = i / per, j = i % per;
    const void* s = (m == 0) ? s0 : (m == 1) ? s1 : s2;
    bf16* d = (m == 0) ? d0 : (m == 1) ? d1 : d2;
    if (flag[0]) {
        ((uint4*)d)[j] = ((const uint4*)s)[j];
    } else {
        const float4* f = (const float4*)s;
        float4 a = f[2 * j], b = f[2 * j + 1];
        short8 o;
        float va[8] = {a.x, a.y, a.z, a.w, b.x, b.y, b.z, b.w};
#pragma unroll
        for (int k = 0; k < 8; k++) o[k] = f2bfu(va[k]);
        ((short8*)d)[j] = o;
    }
}

// ---------------- gather embeddings: Vp (raw) and U=LN(row), both bf16 ----------------
__global__ __launch_bounds__(256) void k_gather_ln(const void* __restrict__ emb,
                                                   const int* __restrict__ idx,
                                                   bf16* __restrict__ Vpb,
                                                   bf16* __restrict__ Ub,
                                                   const int* __restrict__ flag) {
    __shared__ float s4[4];
    int r = blockIdx.x, d = threadIdx.x;
    int tok = idx[r];
    long o = (long)tok * DD + d;
    float e = flag[0] ? __bfloat162float(((const bf16*)emb)[o]) : ((const float*)emb)[o];
    Vpb[(long)r * DD + d] = __float2bfloat16(e);
    float m = blk_sum_256(e, s4) * (1.0f / DD);
    float zc = e - m;
    float var = blk_sum_256(zc * zc, s4) * (1.0f / (DD - 1));
    Ub[(long)r * DD + d] = __float2bfloat16(zc / (sqrtf(fmaxf(var, 0.f)) + EPS));
}

// ---------------- per-batch transpose Ub[b][t][d] -> Ut[b][d][t] ----------------
__global__ __launch_bounds__(256) void k_transpose(const bf16* __restrict__ Ub,
                                                   bf16* __restrict__ Ut) {
    __shared__ bf16 tile[32][33];
    int b = blockIdx.z;
    int t0 = blockIdx.x * 32, d0 = blockIdx.y * 32;
    const bf16* src = Ub + (long)b * TT * DD;
    bf16* dst = Ut + (long)b * DD * TT;
    int rr = threadIdx.x >> 3, c4 = (threadIdx.x & 7) * 4;
#pragma unroll
    for (int i = 0; i < 4; i++) tile[rr][c4 + i] = src[(long)(t0 + rr) * DD + d0 + c4 + i];
    __syncthreads();
#pragma unroll
    for (int i = 0; i < 4; i++) dst[(long)(d0 + rr) * TT + t0 + c4 + i] = tile[c4 + i][rr];
}

// =====================================================================
// k_g128: 128x128 tile, K=256 (4 iters of BK=64), dbuf gl16 staging with
// ONE barrier per iter; XOR-swizzled LDS; coalesced bf16 repack epilogue.
// =====================================================================
enum { EPI_RELU_BF16 = 0, EPI_RELU_MULX_BF16 = 2 };

template <int EPI>
__global__ __launch_bounds__(256) void k_g128(const bf16* __restrict__ A,
                                              const bf16* __restrict__ B,
                                              bf16* __restrict__ C,
                                              const bf16* __restrict__ Xaux,
                                              float* __restrict__ Wsum) {
    __shared__ __align__(16) char smem[65536];  // [buf][A 16K | B 16K]
    const int lda = DD, ldb = DD, ldc = NN;
    int bm = blockIdx.y * 128, bn = blockIdx.x * 128;
    int tid = threadIdx.x, w = tid >> 6, lane = tid & 63;
    int lrow = lane >> 3, lph = lane & 7;
    int rr0 = w * 32;
    int csw = lph ^ lrow;  // xor-swizzled logical chunk for staging

    floatx4 acc[4][4];
#pragma unroll
    for (int i = 0; i < 4; i++)
#pragma unroll
        for (int j = 0; j < 4; j++) acc[i][j] = (floatx4){0.f, 0.f, 0.f, 0.f};

#define STAGE128(buf, k0)                                                              \
    {                                                                                  \
        char* bb = smem + (buf)*32768;                                                 \
        _Pragma("unroll") for (int j = 0; j < 4; j++) {                                \
            int row = rr0 + j * 8 + lrow;                                              \
            gl16(A + (long)(bm + row) * lda + (k0) + csw * 8,                          \
                 bb + (rr0 + j * 8) * 128 + lane * 16);                                \
            gl16(B + (long)(bn + row) * ldb + (k0) + csw * 8,                          \
                 bb + 16384 + (rr0 + j * 8) * 128 + lane * 16);                        \
        }                                                                              \
    }

    int wm = (w >> 1) * 64, wn = (w & 1) * 64;
    int lm = lane & 15, kh = lane >> 4;

    STAGE128(0, 0);
#pragma unroll
    for (int it = 0; it < 4; it++) {
        __syncthreads();  // drains prefetch into buf it&1
        if (it < 3) STAGE128((it + 1) & 1, (it + 1) * 64);
        char* Ab = smem + (it & 1) * 32768;
        char* Bb = Ab + 16384;
#pragma unroll
        for (int ks = 0; ks < 2; ks++) {
            int c = ks * 4 + kh;
            short8 af[4], bfr[4];
#pragma unroll
            for (int i = 0; i < 4; i++) af[i] = frag(Ab, wm + i * 16 + lm, c);
#pragma unroll
            for (int j = 0; j < 4; j++) bfr[j] = frag(Bb, wn + j * 16 + lm, c);
#pragma unroll
            for (int i = 0; i < 4; i++)
#pragma unroll
                for (int j = 0; j < 4; j++)
                    acc[i][j] = __builtin_amdgcn_mfma_f32_16x16x32_bf16(af[i], bfr[j], acc[i][j], 0, 0, 0);
        }
    }
#undef STAGE128

    // ---- LDS repack epilogue: two 64-row passes, coalesced 16B stores ----
    bf16* R = (bf16*)smem;  // [64][136]
#pragma unroll
    for (int p = 0; p < 2; p++) {
        __syncthreads();
        if ((w >> 1) == p) {
#pragma unroll
            for (int i = 0; i < 4; i++)
#pragma unroll
                for (int j = 0; j < 4; j++)
#pragma unroll
                    for (int r = 0; r < 4; r++) {
                        int rr = i * 16 + kh * 4 + r;
                        int cc = wn + j * 16 + lm;
                        R[rr * 136 + cc] = __float2bfloat16(fmaxf(acc[i][j][r], 0.f));
                    }
        }
        __syncthreads();
#pragma unroll
        for (int it2 = 0; it2 < 4; it2++) {
            int row_l = it2 * 16 + (tid >> 4);
            int c8 = (tid & 15) * 8;
            short8 vv = *(const short8*)(R + row_l * 136 + c8);
            int gm = bm + p * 64 + row_l;
            long off = (long)gm * ldc + bn + c8;
            if (EPI == EPI_RELU_BF16) {
                *(short8*)(C + off) = vv;
                float s = 0.f;
#pragma unroll
                for (int k = 0; k < 8; k++) s += bfu2f(vv[k]);
#pragma unroll
                for (int o = 8; o > 0; o >>= 1) s += __shfl_down(s, o, 16);
                if ((tid & 15) == 0) atomicAdd(&Wsum[gm], s);
            } else {
                short8 xx = *(const short8*)(Xaux + off);
                short8 oo;
#pragma unroll
                for (int k = 0; k < 8; k++) oo[k] = f2bfu(bfu2f(vv[k]) * fmaxf(bfu2f(xx[k]), 0.f));
                *(short8*)(C + off) = oo;
            }
        }
    }
}

// =====================================================================
// k_g64x128: 64x128 tile, whole-K (template iters), dbuf, f32 out, batched.
// =====================================================================
template <int KITERS>
__global__ __launch_bounds__(256) void k_g64x128(const bf16* __restrict__ A, int lda, long sA,
                                                 const bf16* __restrict__ B, int ldb, long sB,
                                                 float* __restrict__ C, int ldc, long sC) {
    __shared__ __align__(16) char smem[49152];  // [buf][A 8K | B 16K]
    int z = blockIdx.z;
    A += (long)z * sA;
    B += (long)z * sB;
    long cbase = (long)z * sC;
    int bm = blockIdx.y * 64, bn = blockIdx.x * 128;
    int tid = threadIdx.x, w = tid >> 6, lane = tid & 63;
    int lrow = lane >> 3, lph = lane & 7;
    int csw = lph ^ lrow;

    floatx4 acc[2][4];
#pragma unroll
    for (int i = 0; i < 2; i++)
#pragma unroll
        for (int j = 0; j < 4; j++) acc[i][j] = (floatx4){0.f, 0.f, 0.f, 0.f};

#define STAGE64128(buf, k0)                                                            \
    {                                                                                  \
        char* bb = smem + (buf)*24576;                                                 \
        _Pragma("unroll") for (int j = 0; j < 2; j++) {                                \
            int row = w * 16 + j * 8 + lrow;                                           \
            gl16(A + (long)(bm + row) * lda + (k0) + csw * 8,                          \
                 bb + (w * 16 + j * 8) * 128 + lane * 16);                             \
        }                                                                              \
        _Pragma("unroll") for (int j = 0; j < 4; j++) {                                \
            int row = w * 32 + j * 8 + lrow;                                           \
            gl16(B + (long)(bn + row) * ldb + (k0) + csw * 8,                          \
                 bb + 8192 + (w * 32 + j * 8) * 128 + lane * 16);                      \
        }                                                                              \
    }

    int wm = (w >> 1) * 32, wn = (w & 1) * 64;
    int lm = lane & 15, kh = lane >> 4;

    STAGE64128(0, 0);
    for (int it = 0; it < KITERS; it++) {
        __syncthreads();
        if (it + 1 < KITERS) STAGE64128((it + 1) & 1, (it + 1) * 64);
        char* Ab = smem + (it & 1) * 24576;
        char* Bb = Ab + 8192;
#pragma unroll
        for (int ks = 0; ks < 2; ks++) {
            int c = ks * 4 + kh;
            short8 af[2], bfr[4];
#pragma unroll
            for (int i = 0; i < 2; i++) af[i] = frag(Ab, wm + i * 16 + lm, c);
#pragma unroll
            for (int j = 0; j < 4; j++) bfr[j] = frag(Bb, wn + j * 16 + lm, c);
#pragma unroll
            for (int i = 0; i < 2; i++)
#pragma unroll
                for (int j = 0; j < 4; j++)
                    acc[i][j] = __builtin_amdgcn_mfma_f32_16x16x32_bf16(af[i], bfr[j], acc[i][j], 0, 0, 0);
        }
    }
#undef STAGE64128

#pragma unroll
    for (int i = 0; i < 2; i++)
#pragma unroll
        for (int j = 0; j < 4; j++)
#pragma unroll
            for (int r = 0; r < 4; r++) {
                int gm = bm + wm + i * 16 + kh * 4 + r;
                int gn = bn + wn + j * 16 + lm;
                C[cbase + (long)gm * ldc + gn] = acc[i][j][r];
            }
}

// =====================================================================
// k_scores: 64x64 lower-tri tiles, K=4096 (64 iters), dbuf, fused causal
// decay mask epilogue -> bf16 G directly (no partials, no reduce pass).
// =====================================================================
__global__ __launch_bounds__(256) void k_scores(const bf16* __restrict__ X,
                                                bf16* __restrict__ G) {
    __shared__ __align__(16) char smem[32768];  // [buf][A 8K | B 8K]
    const int tri_i[10] = {0, 1, 1, 2, 2, 2, 3, 3, 3, 3};
    const int tri_j[10] = {0, 0, 1, 0, 1, 2, 0, 1, 2, 3};
    int z = blockIdx.z;
    const bf16* A = X + (long)z * TT * NN;
    int bm = tri_i[blockIdx.x] * 64, bn = tri_j[blockIdx.x] * 64;
    int tid = threadIdx.x, w = tid >> 6, lane = tid & 63;
    int lrow = lane >> 3, lph = lane & 7;
    int csw = lph ^ lrow;

    floatx4 acc[2][2];
#pragma unroll
    for (int i = 0; i < 2; i++)
#pragma unroll
        for (int j = 0; j < 2; j++) acc[i][j] = (floatx4){0.f, 0.f, 0.f, 0.f};

#define STAGESC(buf, k0)                                                               \
    {                                                                                  \
        char* bb = smem + (buf)*16384;                                                 \
        _Pragma("unroll") for (int j = 0; j < 2; j++) {                                \
            int row = w * 16 + j * 8 + lrow;                                           \
            gl16(A + (long)(bm + row) * NN + (k0) + csw * 8,                           \
                 bb + (w * 16 + j * 8) * 128 + lane * 16);                             \
            gl16(A + (long)(bn + row) * NN + (k0) + csw * 8,                           \
                 bb + 8192 + (w * 16 + j * 8) * 128 + lane * 16);                      \
        }                                                                              \
    }

    int wm = (w >> 1) * 32, wn = (w & 1) * 32;
    int lm = lane & 15, kh = lane >> 4;

    STAGESC(0, 0);
    for (int it = 0; it < 64; it++) {
        __syncthreads();
        if (it < 63) STAGESC((it + 1) & 1, (it + 1) * 64);
        char* Ab = smem + (it & 1) * 16384;
        char* Bb = Ab + 8192;
#pragma unroll
        for (int ks = 0; ks < 2; ks++) {
            int c = ks * 4 + kh;
            short8 af[2], bfr[2];
#pragma unroll
            for (int i = 0; i < 2; i++) af[i] = frag(Ab, wm + i * 16 + lm, c);
#pragma unroll
            for (int j = 0; j < 2; j++) bfr[j] = frag(Bb, wn + j * 16 + lm, c);
#pragma unroll
            for (int i = 0; i < 2; i++)
#pragma unroll
                for (int j = 0; j < 2; j++)
                    acc[i][j] = __builtin_amdgcn_mfma_f32_16x16x32_bf16(af[i], bfr[j], acc[i][j], 0, 0, 0);
        }
    }
#undef STAGESC

    bf16* Gb = G + (long)z * TT * TT;
#pragma unroll
    for (int i = 0; i < 2; i++)
#pragma unroll
        for (int j = 0; j < 2; j++)
#pragma unroll
            for (int r = 0; r < 4; r++) {
                int gt = bm + wm + i * 16 + kh * 4 + r;
                int gs = bn + wn + j * 16 + lm;
                float v = (gs < gt) ? acc[i][j][r] * exp2f((float)(gt - gs) * LOG2_DECAY) : 0.f;
                Gb[(long)gt * TT + gs] = __float2bfloat16(v);
            }
}

// ---------------- scalar normalizer recurrence ----------------
__global__ __launch_bounds__(256) void k_scalar_scan(const float* __restrict__ Wsum,
                                                     float* __restrict__ invS) {
    __shared__ float sw[BB * TT];
    for (int i = threadIdx.x; i < BB * TT; i += 256) sw[i] = Wsum[i];
    __syncthreads();
    int b = threadIdx.x;
    if (b < BB) {
        float sig = 0.f;
        for (int t = 0; t < TT; t++) {
            float S = DECAY * sig + sw[b * TT + t];
            float inv = 1.f / (S + EPS);
            invS[b * TT + t] = inv;
            sig = S * inv;
        }
    }
}

// ---------------- column scan, 1 column/thread, 4-deep load prefetch ----------------
__global__ __launch_bounds__(256) void k_colscan(bf16* __restrict__ W,
                                                 const float* __restrict__ invS) {
    __shared__ float sv[TT];
    int b = blockIdx.y;
    sv[threadIdx.x] = invS[b * TT + threadIdx.x];
    __syncthreads();
    int n = blockIdx.x * 256 + threadIdx.x;
    bf16* p = W + (long)b * TT * NN + n;
    float x = 0.f;
    for (int t = 0; t < TT; t += 4) {
        short w0 = *(const short*)(p + (long)t * NN);
        short w1 = *(const short*)(p + (long)(t + 1) * NN);
        short w2 = *(const short*)(p + (long)(t + 2) * NN);
        short w3 = *(const short*)(p + (long)(t + 3) * NN);
        x = (DECAY * x + bfu2f(w0)) * sv[t];
        *(short*)(p + (long)t * NN) = f2bfu(x);
        x = (DECAY * x + bfu2f(w1)) * sv[t + 1];
        *(short*)(p + (long)(t + 1) * NN) = f2bfu(x);
        x = (DECAY * x + bfu2f(w2)) * sv[t + 2];
        *(short*)(p + (long)(t + 2) * NN) = f2bfu(x);
        x = (DECAY * x + bfu2f(w3)) * sv[t + 3];
        *(short*)(p + (long)(t + 3) * NN) = f2bfu(x);
    }
}

// ---------------- row layernorm Astar (fp32) -> ALN bf16 ----------------
__global__ __launch_bounds__(256) void k_ln_rows(const float* __restrict__ Z,
                                                 bf16* __restrict__ O) {
    __shared__ float s4[4];
    long r = blockIdx.x;
    int d = threadIdx.x;
    float z = Z[r * DD + d];
    float m = blk_sum_256(z, s4) * (1.0f / DD);
    float zc = z - m;
    float var = blk_sum_256(zc * zc, s4) * (1.0f / (DD - 1));
    O[r * DD + d] = __float2bfloat16(zc / (sqrtf(fmaxf(var, 0.f)) + EPS));
}

// ---------------- final layernorm (single f32 Z buffer) -> output ----------------
__global__ __launch_bounds__(256) void k_final_ln(const float* __restrict__ Zf,
                                                  void* __restrict__ out,
                                                  const int* __restrict__ flag) {
    __shared__ float s4[4];
    long r = blockIdx.x;
    int d = threadIdx.x;
    long o = r * DD + d;
    float z = Zf[o];
    float m = blk_sum_256(z, s4) * (1.0f / DD);
    float zc = z - m;
    float var = blk_sum_256(zc * zc, s4) * (1.0f / (DD - 1));
    float v = zc / (sqrtf(fmaxf(var, 0.f)) + EPS);
    if (flag[0]) ((bf16*)out)[o] = __float2bfloat16(v);
    else ((float*)out)[o] = v;
}

extern "C" void kernel_launch(void* const* d_in, const int* in_sizes, int n_in,
                              void* d_out, int out_size, void* d_ws, size_t ws_size,
                              hipStream_t stream) {
    const int* idx = (const int*)d_in[0];
    const void* emb = d_in[1];
    const void* E = d_in[2];
    const void* Dx = d_in[3];
    const void* Dy = d_in[4];

    // ---- workspace carve (bytes) ----
    char* base = (char*)d_ws;
    size_t off = 0;
    int* flag = (int*)base; off += 1024;
    bf16* Dxb = (bf16*)(base + off); off += (size_t)NN * DD * 2;
    bf16* Dyb = (bf16*)(base + off); off += (size_t)NN * DD * 2;
    bf16* Eb  = (bf16*)(base + off); off += (size_t)DD * NN * 2;
    bf16* Vpb = (bf16*)(base + off); off += (size_t)BB * TT * DD * 2;
    bf16* Ub  = (bf16*)(base + off); off += (size_t)BB * TT * DD * 2;
    bf16* Ut  = (bf16*)(base + off); off += (size_t)BB * TT * DD * 2;
    float* Wsum = (float*)(base + off); off += (size_t)BB * TT * 4;
    float* invS = (float*)(base + off); off += (size_t)BB * TT * 4;
    bf16* ALNb = (bf16*)(base + off); off += (size_t)BB * TT * DD * 2;
    bf16* G = (bf16*)(base + off); off += (size_t)BB * TT * TT * 2;       // 4MB
    float* Astar = (float*)(base + off); off += (size_t)BB * TT * DD * 4; // 8.4MB
    float* Zf = (float*)(base + off); off += (size_t)BB * TT * DD * 4;    // 8.4MB
    bf16* Xb = (bf16*)(base + off); off += (size_t)BB * TT * NN * 2;      // 67MB

    const int M = BB * TT;  // 8192

    k_detect<<<1, 256, 0, stream>>>((const unsigned short*)emb, flag);
    k_convert3<<<3 * NN * DD / 8 / 256, 256, 0, stream>>>(Dx, Dy, E, Dxb, Dyb, Eb, flag);
    k_gather_ln<<<M, 256, 0, stream>>>(emb, idx, Vpb, Ub, flag);
    k_transpose<<<dim3(8, 8, BB), 256, 0, stream>>>(Ub, Ut);

    hipMemsetAsync(Wsum, 0, (size_t)M * 4, stream);
    hipMemsetAsync(G, 0, (size_t)BB * TT * TT * 2, stream);

    // W = relu(Vp @ Dx^T) -> Xb (bf16), rowsums fused via atomics
    k_g128<EPI_RELU_BF16><<<dim3(NN / 128, M / 128, 1), 256, 0, stream>>>(
        Vpb, Dxb, Xb, nullptr, Wsum);

    k_scalar_scan<<<1, 256, 0, stream>>>(Wsum, invS);
    k_colscan<<<dim3(NN / 256, BB, 1), 256, 0, stream>>>(Xb, invS);

    // scores: lower-tri 64x64 tiles, fused decay mask -> G bf16 (upper zeroed by memset)
    k_scores<<<dim3(10, 1, BB), 256, 0, stream>>>(Xb, G);

    // a* = Gm @ U (NT with Ut), batched, whole-K=256 -> f32 Astar
    k_g64x128<4><<<dim3(DD / 128, TT / 64, BB), 256, 0, stream>>>(
        G, TT, (long)TT * TT, Ut, TT, (long)DD * TT, Astar, DD, (long)TT * DD);
    k_ln_rows<<<M, 256, 0, stream>>>(Astar, ALNb);

    // Y = relu(ALN @ Dy^T) * relu(X), in place over Xb
    k_g128<EPI_RELU_MULX_BF16><<<dim3(NN / 128, M / 128, 1), 256, 0, stream>>>(
        ALNb, Dyb, Xb, Xb, nullptr);

    // Z = Y @ E^T, whole-K=4096 -> f32 Zf (no partials)
    k_g64x128<64><<<dim3(DD / 128, M / 64, 1), 256, 0, stream>>>(
        Xb, NN, 0, Eb, NN, 0, Zf, DD, 0);

    k_final_ln<<<M, 256, 0, stream>>>(Zf, d_out, flag);
}